// Round 14
// baseline (1169.782 us; speedup 1.0000x reference)
//
#include <hip/hip_runtime.h>
#include <hip/hip_bf16.h>

typedef __attribute__((ext_vector_type(4)))  float  floatx4;
typedef __attribute__((ext_vector_type(16))) float  floatx16;
typedef __attribute__((ext_vector_type(8)))  short  shortx8;
typedef __attribute__((ext_vector_type(4)))  short  shortx4;

// ---------- bf16 helpers (bit-level, RNE) ----------
__device__ __forceinline__ short f2bf(float f) {
    unsigned u = __float_as_uint(f);
    u += 0x7fffu + ((u >> 16) & 1u);
    return (short)(u >> 16);
}
__device__ __forceinline__ float bf2f(short s) {
    return __uint_as_float(((unsigned)(unsigned short)s) << 16);
}
__device__ __forceinline__ float fast_exp2(float x) {
#if __has_builtin(__builtin_amdgcn_exp2f)
    return __builtin_amdgcn_exp2f(x);
#else
    return exp2f(x);
#endif
}

// ---------- async global->LDS, 16B per lane ----------
__device__ __forceinline__ void load_lds16(const void* g, void* l) {
    __builtin_amdgcn_global_load_lds(
        (const __attribute__((address_space(1))) unsigned int*)g,
        (__attribute__((address_space(3))) unsigned int*)l,
        16, 0, 0);
}

// =====================================================================
// Weight transpose+convert: src fp32 [K][N] -> dst bf16 [N][K]
// =====================================================================
__global__ __launch_bounds__(256)
void transpose_w(const float* __restrict__ src, short* __restrict__ dst, int K, int N)
{
    __shared__ __align__(16) float tile[32][33];
    const int n0 = blockIdx.x * 32, k0 = blockIdx.y * 32;
    const int tx = threadIdx.x & 31, ty = threadIdx.x >> 5;   // ty 0..7
    for (int i = 0; i < 32; i += 8)
        tile[ty + i][tx] = src[(size_t)(k0 + ty + i) * N + n0 + tx];
    __syncthreads();
    for (int i = 0; i < 32; i += 8)
        dst[(size_t)(n0 + ty + i) * K + k0 + tx] = f2bf(tile[tx][ty + i]);
}

// =====================================================================
// LayerNorm fp32 [8192][1024] -> bf16, 1 block/row
// =====================================================================
__global__ __launch_bounds__(256)
void ln_bf16(const float* __restrict__ x, const float* __restrict__ g,
             const float* __restrict__ be, short* __restrict__ out)
{
    const int row = blockIdx.x;
    const int tid = threadIdx.x;
    const float4 v = reinterpret_cast<const float4*>(x + (size_t)row * 1024)[tid];
    float s  = v.x + v.y + v.z + v.w;
    float ss = v.x * v.x + v.y * v.y + v.z * v.z + v.w * v.w;
    for (int off = 32; off > 0; off >>= 1) {
        s  += __shfl_down(s,  off);
        ss += __shfl_down(ss, off);
    }
    __shared__ float rs[4], rss[4];
    const int wave = tid >> 6, lane = tid & 63;
    if (lane == 0) { rs[wave] = s; rss[wave] = ss; }
    __syncthreads();
    const float S    = rs[0] + rs[1] + rs[2] + rs[3];
    const float SS   = rss[0] + rss[1] + rss[2] + rss[3];
    const float mean = S * (1.0f / 1024.0f);
    const float var  = SS * (1.0f / 1024.0f) - mean * mean;
    const float rstd = rsqrtf(var + 1e-5f);
    const float4 gg = reinterpret_cast<const float4*>(g)[tid];
    const float4 bb = reinterpret_cast<const float4*>(be)[tid];
    shortx4 o;
    o[0] = f2bf(gg.x * ((v.x - mean) * rstd) + bb.x);
    o[1] = f2bf(gg.y * ((v.y - mean) * rstd) + bb.y);
    o[2] = f2bf(gg.z * ((v.z - mean) * rstd) + bb.z);
    o[3] = f2bf(gg.w * ((v.w - mean) * rstd) + bb.w);
    *reinterpret_cast<shortx4*>(out + (size_t)row * 1024 + tid * 4) = o;
}

// =====================================================================
// 128x128 bf16 GEMM, BK=64 (R12 measured-best config) -- used for the
// smaller-grid GEMMs (Wo, FF2) where 256-tile would drop residency.
// 256 threads = 4 waves (2x2, 64x64), 32 KiB LDS, 4 blocks/CU.
// EPI 0: store bf16
// EPI 1: +bias, relu, store bf16
// EPI 2: fp32 out = resid + acc
// EPI 4: atomicAdd(out, acc (+bias if sp==0))   -- split-K
// =====================================================================
template <int EPI>
__global__ __launch_bounds__(256, 4)
void gemm_bt(const short* __restrict__ A, const short* __restrict__ Bt,
             short* __restrict__ Cb, float* __restrict__ Cf,
             const float* __restrict__ bias, const float* __restrict__ resid,
             int M, int N, int K, int tilesN, int nsplit)
{
    __shared__ __align__(16) short As[128 * 64];   // 16 KiB
    __shared__ __align__(16) short Bs[128 * 64];   // 16 KiB

    int wg = blockIdx.x;
    {
        const int nwg = gridDim.x;
        const int q = nwg >> 3, r = nwg & 7;
        const int xcd = wg & 7, loc = wg >> 3;
        wg = (xcd < r ? xcd * (q + 1) : r * (q + 1) + (xcd - r) * q) + loc;
    }
    const int ntiles = gridDim.x / nsplit;
    const int sp   = wg / ntiles;
    const int tile = wg - sp * ntiles;
    const int tm = tile / tilesN, tn = tile - tm * tilesN;
    const size_t bm = (size_t)tm * 128, bn = (size_t)tn * 128;
    const int Ks   = K / nsplit;
    const int kbeg = sp * Ks;

    const int tid  = threadIdx.x;
    const int wave = tid >> 6;
    const int lane = tid & 63;
    const int quad = lane >> 4;
    const int l16  = lane & 15;
    const int wm = wave >> 1, wn = wave & 1;

    floatx4 acc[4][4];
#pragma unroll
    for (int i = 0; i < 4; i++)
#pragma unroll
        for (int j = 0; j < 4; j++)
            acc[i][j] = (floatx4){0.f, 0.f, 0.f, 0.f};

    const int srow = tid >> 3;               // 0..31
    const int gsrc = (tid & 7) ^ (srow & 7);
    const short* sA = A  + (bm + srow) * (size_t)K + kbeg + gsrc * 8;
    const short* sB = Bt + (bn + srow) * (size_t)K + kbeg + gsrc * 8;
    const int dstw = wave * 512;

    const int g0 = ((quad    ) ^ (l16 & 7)) * 8;
    const int g1 = ((quad + 4) ^ (l16 & 7)) * 8;

    for (int k0 = 0; k0 < Ks; k0 += 64) {
#pragma unroll
        for (int c = 0; c < 4; ++c)
            load_lds16(sA + (size_t)(c * 32) * K + k0, &As[c * 2048 + dstw]);
#pragma unroll
        for (int c = 0; c < 4; ++c)
            load_lds16(sB + (size_t)(c * 32) * K + k0, &Bs[c * 2048 + dstw]);
        __syncthreads();
        {
            shortx8 af[4], bf[4];
#pragma unroll
            for (int mi = 0; mi < 4; mi++)
                af[mi] = *(const shortx8*)&As[(wm * 64 + mi * 16 + l16) * 64 + g0];
#pragma unroll
            for (int ni = 0; ni < 4; ni++)
                bf[ni] = *(const shortx8*)&Bs[(wn * 64 + ni * 16 + l16) * 64 + g0];
#pragma unroll
            for (int mi = 0; mi < 4; mi++)
#pragma unroll
                for (int ni = 0; ni < 4; ni++)
                    acc[mi][ni] = __builtin_amdgcn_mfma_f32_16x16x32_bf16(
                        af[mi], bf[ni], acc[mi][ni], 0, 0, 0);
        }
        {
            shortx8 af[4], bf[4];
#pragma unroll
            for (int mi = 0; mi < 4; mi++)
                af[mi] = *(const shortx8*)&As[(wm * 64 + mi * 16 + l16) * 64 + g1];
#pragma unroll
            for (int ni = 0; ni < 4; ni++)
                bf[ni] = *(const shortx8*)&Bs[(wn * 64 + ni * 16 + l16) * 64 + g1];
#pragma unroll
            for (int mi = 0; mi < 4; mi++)
#pragma unroll
                for (int ni = 0; ni < 4; ni++)
                    acc[mi][ni] = __builtin_amdgcn_mfma_f32_16x16x32_bf16(
                        af[mi], bf[ni], acc[mi][ni], 0, 0, 0);
        }
        __syncthreads();
    }

#pragma unroll
    for (int mi = 0; mi < 4; mi++) {
#pragma unroll
        for (int ni = 0; ni < 4; ni++) {
            const size_t row0 = bm + wm * 64 + mi * 16 + quad * 4;
            const size_t col  = bn + wn * 64 + ni * 16 + l16;
#pragma unroll
            for (int r2 = 0; r2 < 4; r2++) {
                float v = acc[mi][ni][r2];
                const size_t idx = (row0 + r2) * (size_t)N + col;
                if (EPI == 0) {
                    Cb[idx] = f2bf(v);
                } else if (EPI == 1) {
                    v += bias[col];
                    Cb[idx] = f2bf(v > 0.f ? v : 0.f);
                } else if (EPI == 2) {
                    Cf[idx] = resid[idx] + v;
                } else {  // EPI 4
                    if (sp == 0) v += bias[col];
                    atomicAdd(&Cf[idx], v);
                }
            }
        }
    }
}

// =====================================================================
// 256x128 bf16 GEMM, BK=64: higher arithmetic intensity (0.75x staged
// bytes vs 128x128) at maintained residency.
// 512 threads = 8 waves (4M x 2N, 64x64 each -> acc 4x4, ~64 VGPR),
// 48 KiB LDS -> 3 blocks/CU (144 KiB), __launch_bounds__(512,6).
// Same XOR-granule swizzle / staging identities as gemm_bt
// (wave*8 == 0 mod 8 keeps gsrc = (lane&7)^((lane>>3)&7)).
// Used for large-grid GEMMs: QKV (768 WGs), FF1 (1024 WGs).
// EPI 0: store bf16;  EPI 1: +bias, relu, store bf16
// =====================================================================
template <int EPI>
__global__ __launch_bounds__(512, 6)
void gemm_big(const short* __restrict__ A, const short* __restrict__ Bt,
              short* __restrict__ Cb, float* __restrict__ Cf,
              const float* __restrict__ bias, const float* __restrict__ resid,
              int M, int N, int K, int tilesN, int nsplit)
{
    __shared__ __align__(16) short As[256 * 64];   // 32 KiB
    __shared__ __align__(16) short Bs[128 * 64];   // 16 KiB

    int wg = blockIdx.x;
    {
        const int nwg = gridDim.x;
        const int q = nwg >> 3, r = nwg & 7;
        const int xcd = wg & 7, loc = wg >> 3;
        wg = (xcd < r ? xcd * (q + 1) : r * (q + 1) + (xcd - r) * q) + loc;
    }
    const int ntiles = gridDim.x / nsplit;
    const int sp   = wg / ntiles;
    const int tile = wg - sp * ntiles;
    const int tm = tile / tilesN, tn = tile - tm * tilesN;
    const size_t bm = (size_t)tm * 256, bn = (size_t)tn * 128;
    const int Ks   = K / nsplit;
    const int kbeg = sp * Ks;

    const int tid  = threadIdx.x;
    const int wave = tid >> 6;          // 0..7
    const int lane = tid & 63;
    const int quad = lane >> 4;
    const int l16  = lane & 15;
    const int wm = wave >> 1, wn = wave & 1;   // 4M x 2N, 64x64 per wave

    floatx4 acc[4][4];
#pragma unroll
    for (int i = 0; i < 4; i++)
#pragma unroll
        for (int j = 0; j < 4; j++)
            acc[i][j] = (floatx4){0.f, 0.f, 0.f, 0.f};

    // staging: 512 threads -> row = c*64 + (tid>>3) (0..63), slot = tid&7.
    // source granule pre-swizzled: (tid&7) ^ ((tid>>3)&7) == slot ^ (row&7).
    const int srow = tid >> 3;               // 0..63
    const int gsrc = (tid & 7) ^ (srow & 7);
    const short* sA = A  + (bm + srow) * (size_t)K + kbeg + gsrc * 8;
    const short* sB = Bt + (bn + srow) * (size_t)K + kbeg + gsrc * 8;
    const int dstw = wave * 512;             // 8 waves x 512 shorts = 4096/call

    const int g0 = ((quad    ) ^ (l16 & 7)) * 8;
    const int g1 = ((quad + 4) ^ (l16 & 7)) * 8;

    for (int k0 = 0; k0 < Ks; k0 += 64) {
        // A: 4 calls x 64 rows; B: 2 calls x 64 rows (each call 4096 shorts)
#pragma unroll
        for (int c = 0; c < 4; ++c)
            load_lds16(sA + (size_t)(c * 64) * K + k0, &As[c * 4096 + dstw]);
#pragma unroll
        for (int c = 0; c < 2; ++c)
            load_lds16(sB + (size_t)(c * 64) * K + k0, &Bs[c * 4096 + dstw]);
        __syncthreads();
        {
            shortx8 af[4], bf[4];
#pragma unroll
            for (int mi = 0; mi < 4; mi++)
                af[mi] = *(const shortx8*)&As[(wm * 64 + mi * 16 + l16) * 64 + g0];
#pragma unroll
            for (int ni = 0; ni < 4; ni++)
                bf[ni] = *(const shortx8*)&Bs[(wn * 64 + ni * 16 + l16) * 64 + g0];
#pragma unroll
            for (int mi = 0; mi < 4; mi++)
#pragma unroll
                for (int ni = 0; ni < 4; ni++)
                    acc[mi][ni] = __builtin_amdgcn_mfma_f32_16x16x32_bf16(
                        af[mi], bf[ni], acc[mi][ni], 0, 0, 0);
        }
        {
            shortx8 af[4], bf[4];
#pragma unroll
            for (int mi = 0; mi < 4; mi++)
                af[mi] = *(const shortx8*)&As[(wm * 64 + mi * 16 + l16) * 64 + g1];
#pragma unroll
            for (int ni = 0; ni < 4; ni++)
                bf[ni] = *(const shortx8*)&Bs[(wn * 64 + ni * 16 + l16) * 64 + g1];
#pragma unroll
            for (int mi = 0; mi < 4; mi++)
#pragma unroll
                for (int ni = 0; ni < 4; ni++)
                    acc[mi][ni] = __builtin_amdgcn_mfma_f32_16x16x32_bf16(
                        af[mi], bf[ni], acc[mi][ni], 0, 0, 0);
        }
        __syncthreads();
    }

#pragma unroll
    for (int mi = 0; mi < 4; mi++) {
#pragma unroll
        for (int ni = 0; ni < 4; ni++) {
            const size_t row0 = bm + wm * 64 + mi * 16 + quad * 4;
            const size_t col  = bn + wn * 64 + ni * 16 + l16;
#pragma unroll
            for (int r2 = 0; r2 < 4; r2++) {
                float v = acc[mi][ni][r2];
                const size_t idx = (row0 + r2) * (size_t)N + col;
                if (EPI == 0) {
                    Cb[idx] = f2bf(v);
                } else {  // EPI 1
                    v += bias[col];
                    Cb[idx] = f2bf(v > 0.f ? v : 0.f);
                }
            }
        }
    }
}

// =====================================================================
// V transpose: qkv v-part -> vt[b][h][64 d][2048 s] bf16
// =====================================================================
__global__ __launch_bounds__(256)
void transpose_v(const short* __restrict__ qkv, short* __restrict__ vt)
{
    __shared__ __align__(16) short tile[64][65];
    const int st = blockIdx.x, h = blockIdx.y, b = blockIdx.z;
    const int t = threadIdx.x;
    for (int i = 0; i < 2; i++) {
        const int idx = i * 256 + t;
        const int s = idx >> 3, dg = idx & 7;
        shortx8 val = *(const shortx8*)&qkv[(size_t)(b * 2048 + st * 64 + s) * 3072
                                           + 2048 + h * 64 + dg * 8];
        for (int u = 0; u < 8; u++) tile[s][dg * 8 + u] = val[u];
    }
    __syncthreads();
    const int d = t >> 2, sg = (t & 3) * 16;
    shortx8 lo, hi;
    for (int i = 0; i < 8; i++) {
        lo[i] = tile[sg + i][d];
        hi[i] = tile[sg + 8 + i][d];
    }
    const size_t base = ((size_t)(b * 16 + h) * 64 + d) * 2048 + st * 64 + sg;
    *(shortx8*)&vt[base]     = lo;
    *(shortx8*)&vt[base + 8] = hi;
}

// =====================================================================
// Flash attention v6 (unchanged): 32x32x16 MFMA, 8 waves x 32 q-rows.
// =====================================================================
__global__ __launch_bounds__(512, 4)
void attention_kernel(const short* __restrict__ qkv, const short* __restrict__ vt,
                      short* __restrict__ ctx)
{
    const int qt = blockIdx.x, h = blockIdx.y, b = blockIdx.z;
    const int tid  = threadIdx.x;
    const int wave = tid >> 6;          // 0..7
    const int lane = tid & 63;
    const int l32  = lane & 31;
    const int hf   = lane >> 5;         // 0/1

    __shared__ __align__(16) short Ks[64 * 72];        // [kseq][d], stride 72
    __shared__ __align__(16) short Vs[64 * 72];        // [d][s],   stride 72
    __shared__ __align__(16) short Ps[8][32 * 72];     // per-wave P [q][s], stride 72

    const int q0 = qt * 256 + wave * 32;
    const float qscale = 0.125f * 1.44269504088896f;
    const short* qrow = qkv + (size_t)(b * 2048 + q0 + l32) * 3072 + h * 64;
    shortx8 qf[4];
    for (int dk = 0; dk < 4; dk++) {
        shortx8 raw = *(const shortx8*)&qrow[dk * 16 + hf * 8];
        for (int j = 0; j < 8; j++) raw[j] = f2bf(bf2f(raw[j]) * qscale);
        qf[dk] = raw;
    }

    floatx16 accO[2];
    for (int t = 0; t < 2; t++)
        for (int r = 0; r < 16; r++) accO[t][r] = 0.f;
    float lsum = 0.f;

    const short* kbase = qkv + (size_t)(b * 2048) * 3072 + 1024 + h * 64;
    const short* vbase = vt + ((size_t)(b * 16 + h) * 64) * 2048;
    short* const psw = &Ps[wave][0];
    unsigned* const pswd = (unsigned*)psw;

    const int ss = tid >> 3, sdg = tid & 7;

    for (int kt = 0; kt < 32; ++kt) {
        __syncthreads();
        {
            shortx8 kv = *(const shortx8*)&kbase[(size_t)(kt * 64 + ss) * 3072 + sdg * 8];
            *(shortx8*)&Ks[ss * 72 + sdg * 8] = kv;
            shortx8 vv = *(const shortx8*)&vbase[(size_t)ss * 2048 + kt * 64 + sdg * 8];
            *(shortx8*)&Vs[ss * 72 + sdg * 8] = vv;
        }
        __syncthreads();

        for (int t = 0; t < 2; t++) {
            floatx16 c;
            for (int r = 0; r < 16; r++) c[r] = 0.f;
            for (int dk = 0; dk < 4; dk++) {
                shortx8 kf = *(const shortx8*)&Ks[(t * 32 + l32) * 72 + dk * 16 + hf * 8];
                c = __builtin_amdgcn_mfma_f32_32x32x16_bf16(kf, qf[dk], c, 0, 0, 0);
            }
            for (int R = 0; R < 4; R++) {
                float2 a, bb;
                a.x  = fast_exp2(c[4 * R + 0]);
                a.y  = fast_exp2(c[4 * R + 1]);
                bb.x = fast_exp2(c[4 * R + 2]);
                bb.y = fast_exp2(c[4 * R + 3]);
                lsum += (a.x + a.y) + (bb.x + bb.y);
                union { __hip_bfloat162 h2[2]; uint2 u; } pk;
                pk.h2[0] = __float22bfloat162_rn(a);
                pk.h2[1] = __float22bfloat162_rn(bb);
                *(uint2*)&pswd[l32 * 36 + t * 16 + 4 * R + 2 * hf] = pk.u;
            }
        }
        asm volatile("s_waitcnt lgkmcnt(0)" ::: "memory");

        shortx8 pf[4];
        for (int sk = 0; sk < 4; sk++)
            pf[sk] = *(const shortx8*)&psw[l32 * 72 + sk * 16 + hf * 8];

        for (int t = 0; t < 2; t++) {
            floatx16 c = accO[t];
            for (int sk = 0; sk < 4; sk++) {
                shortx8 vf = *(const shortx8*)&Vs[(t * 32 + l32) * 72 + sk * 16 + hf * 8];
                c = __builtin_amdgcn_mfma_f32_32x32x16_bf16(vf, pf[sk], c, 0, 0, 0);
            }
            accO[t] = c;
        }
    }

    const float lfull = lsum + __shfl_xor(lsum, 32);
    const float inv = 1.0f / lfull;
    const size_t crow = (size_t)(b * 2048 + q0 + l32) * 1024 + h * 64;
    for (int t = 0; t < 2; t++)
        for (int R = 0; R < 4; R++) {
            float2 a, bb;
            a.x  = accO[t][4 * R + 0] * inv;
            a.y  = accO[t][4 * R + 1] * inv;
            bb.x = accO[t][4 * R + 2] * inv;
            bb.y = accO[t][4 * R + 3] * inv;
            union { __hip_bfloat162 h2[2]; uint2 u; } pk;
            pk.h2[0] = __float22bfloat162_rn(a);
            pk.h2[1] = __float22bfloat162_rn(bb);
            *(uint2*)&ctx[crow + t * 32 + 8 * R + 4 * hf] = pk.u;
        }
}

// =====================================================================
// launch
// =====================================================================
extern "C" void kernel_launch(void* const* d_in, const int* in_sizes, int n_in,
                              void* d_out, int out_size, void* d_ws, size_t ws_size,
                              hipStream_t stream)
{
    const float* x   = (const float*)d_in[0];
    const float* Wq  = (const float*)d_in[1];
    const float* Wk  = (const float*)d_in[2];
    const float* Wv  = (const float*)d_in[3];
    const float* Wo  = (const float*)d_in[4];
    const float* W1  = (const float*)d_in[5];
    const float* b1  = (const float*)d_in[6];
    const float* W2  = (const float*)d_in[7];
    const float* b2  = (const float*)d_in[8];
    const float* g1  = (const float*)d_in[9];
    const float* be1 = (const float*)d_in[10];
    const float* g2  = (const float*)d_in[11];
    const float* be2 = (const float*)d_in[12];
    float* out = (float*)d_out;
    char*  ws  = (char*)d_ws;

    const size_t MiB = 1u << 20;
    short* regA   = (short*)(ws);                 // 16 MiB: ln1 -> ctx -> ln2
    short* qkv    = (short*)(ws + 16 * MiB);      // 48 MiB
    short* vt     = (short*)(ws + 64 * MiB);      // 16 MiB
    short* ff1    = qkv;                          // 64 MiB alias (qkv+vt dead)
    short* Wqkv_t = (short*)(ws + 80 * MiB);      // 6 MiB
    short* Wo_t   = (short*)(ws + 86 * MiB);      // 2 MiB
    short* W1_t   = (short*)(ws + 88 * MiB);      // 8 MiB
    short* W2_t   = (short*)(ws + 96 * MiB);      // 8 MiB  (total 104 MiB)

    const dim3 blk(256);

    // weights -> bf16 BT layout
    transpose_w<<<dim3(32, 32),  blk, 0, stream>>>(Wq, Wqkv_t,                  1024, 1024);
    transpose_w<<<dim3(32, 32),  blk, 0, stream>>>(Wk, Wqkv_t + 1024 * 1024,    1024, 1024);
    transpose_w<<<dim3(32, 32),  blk, 0, stream>>>(Wv, Wqkv_t + 2 * 1024 * 1024,1024, 1024);
    transpose_w<<<dim3(32, 32),  blk, 0, stream>>>(Wo, Wo_t,                    1024, 1024);
    transpose_w<<<dim3(128, 32), blk, 0, stream>>>(W1, W1_t,                    1024, 4096);
    transpose_w<<<dim3(32, 128), blk, 0, stream>>>(W2, W2_t,                    4096, 1024);

    // LN1
    ln_bf16<<<8192, blk, 0, stream>>>(x, g1, be1, regA);
    // QKV: [8192,1024]@[3072,1024]^T -> 256x128 tiles: 32x24 = 768 WGs
    gemm_big<0><<<dim3(768), dim3(512), 0, stream>>>(regA, Wqkv_t, qkv, nullptr,
                                                     nullptr, nullptr, 8192, 3072, 1024, 24, 1);
    // V^T
    transpose_v<<<dim3(32, 16, 4), blk, 0, stream>>>(qkv, vt);
    // attention -> ctx (regA)
    attention_kernel<<<dim3(8, 16, 4), dim3(512), 0, stream>>>(qkv, vt, regA);
    // attn_out @ Wo + x -> out (fp32), fused store: 64x8 = 512 WGs (128^2)
    gemm_bt<2><<<dim3(512), blk, 0, stream>>>(regA, Wo_t, nullptr, out,
                                              nullptr, x, 8192, 1024, 1024, 8, 1);
    // LN2 -> regA
    ln_bf16<<<8192, blk, 0, stream>>>(out, g2, be2, regA);
    // FF1: relu(ln2 @ W1 + b1) -> ff1 (bf16): 256x128 tiles: 32x32 = 1024 WGs
    gemm_big<1><<<dim3(1024), dim3(512), 0, stream>>>(regA, W1_t, ff1, nullptr,
                                                      b1, nullptr, 8192, 4096, 1024, 32, 1);
    // FF2 split-K=2: out += ff1 @ W2 (+b2 on split 0): 64x8x2 = 1024 WGs (128^2)
    gemm_bt<4><<<dim3(1024), blk, 0, stream>>>(ff1, W2_t, nullptr, out,
                                               b2, nullptr, 8192, 1024, 4096, 8, 2);
}

// Round 16
// 520.187 us; speedup vs baseline: 2.2488x; 2.2488x over previous
//
#include <hip/hip_runtime.h>
#include <hip/hip_bf16.h>

typedef __attribute__((ext_vector_type(4)))  float  floatx4;
typedef __attribute__((ext_vector_type(16))) float  floatx16;
typedef __attribute__((ext_vector_type(8)))  short  shortx8;
typedef __attribute__((ext_vector_type(4)))  short  shortx4;

// ---------- bf16 helpers (bit-level, RNE) ----------
__device__ __forceinline__ short f2bf(float f) {
    unsigned u = __float_as_uint(f);
    u += 0x7fffu + ((u >> 16) & 1u);
    return (short)(u >> 16);
}
__device__ __forceinline__ float bf2f(short s) {
    return __uint_as_float(((unsigned)(unsigned short)s) << 16);
}
__device__ __forceinline__ float fast_exp2(float x) {
#if __has_builtin(__builtin_amdgcn_exp2f)
    return __builtin_amdgcn_exp2f(x);
#else
    return exp2f(x);
#endif
}

// ---------- async global->LDS, 16B per lane ----------
__device__ __forceinline__ void load_lds16(const void* g, void* l) {
    __builtin_amdgcn_global_load_lds(
        (const __attribute__((address_space(1))) unsigned int*)g,
        (__attribute__((address_space(3))) unsigned int*)l,
        16, 0, 0);
}

// =====================================================================
// Weight transpose+convert: src fp32 [K][N] -> dst bf16 [N][K]
// =====================================================================
__global__ __launch_bounds__(256)
void transpose_w(const float* __restrict__ src, short* __restrict__ dst, int K, int N)
{
    __shared__ __align__(16) float tile[32][33];
    const int n0 = blockIdx.x * 32, k0 = blockIdx.y * 32;
    const int tx = threadIdx.x & 31, ty = threadIdx.x >> 5;   // ty 0..7
    for (int i = 0; i < 32; i += 8)
        tile[ty + i][tx] = src[(size_t)(k0 + ty + i) * N + n0 + tx];
    __syncthreads();
    for (int i = 0; i < 32; i += 8)
        dst[(size_t)(n0 + ty + i) * K + k0 + tx] = f2bf(tile[tx][ty + i]);
}

// =====================================================================
// LayerNorm fp32 [8192][1024] -> bf16, 1 block/row
// =====================================================================
__global__ __launch_bounds__(256)
void ln_bf16(const float* __restrict__ x, const float* __restrict__ g,
             const float* __restrict__ be, short* __restrict__ out)
{
    const int row = blockIdx.x;
    const int tid = threadIdx.x;
    const float4 v = reinterpret_cast<const float4*>(x + (size_t)row * 1024)[tid];
    float s  = v.x + v.y + v.z + v.w;
    float ss = v.x * v.x + v.y * v.y + v.z * v.z + v.w * v.w;
    for (int off = 32; off > 0; off >>= 1) {
        s  += __shfl_down(s,  off);
        ss += __shfl_down(ss, off);
    }
    __shared__ float rs[4], rss[4];
    const int wave = tid >> 6, lane = tid & 63;
    if (lane == 0) { rs[wave] = s; rss[wave] = ss; }
    __syncthreads();
    const float S    = rs[0] + rs[1] + rs[2] + rs[3];
    const float SS   = rss[0] + rss[1] + rss[2] + rss[3];
    const float mean = S * (1.0f / 1024.0f);
    const float var  = SS * (1.0f / 1024.0f) - mean * mean;
    const float rstd = rsqrtf(var + 1e-5f);
    const float4 gg = reinterpret_cast<const float4*>(g)[tid];
    const float4 bb = reinterpret_cast<const float4*>(be)[tid];
    shortx4 o;
    o[0] = f2bf(gg.x * ((v.x - mean) * rstd) + bb.x);
    o[1] = f2bf(gg.y * ((v.y - mean) * rstd) + bb.y);
    o[2] = f2bf(gg.z * ((v.z - mean) * rstd) + bb.z);
    o[3] = f2bf(gg.w * ((v.w - mean) * rstd) + bb.w);
    *reinterpret_cast<shortx4*>(out + (size_t)row * 1024 + tid * 4) = o;
}

// =====================================================================
// 128x128 bf16 GEMM, BK=64 (R12 measured-best config) -- used for the
// smaller-grid GEMMs (Wo, FF2) where 256-tile would drop residency.
// 256 threads = 4 waves (2x2, 64x64), 32 KiB LDS, 4 blocks/CU.
// EPI 0: store bf16
// EPI 1: +bias, relu, store bf16
// EPI 2: fp32 out = resid + acc
// EPI 4: atomicAdd(out, acc (+bias if sp==0))   -- split-K
// =====================================================================
template <int EPI>
__global__ __launch_bounds__(256, 4)
void gemm_bt(const short* __restrict__ A, const short* __restrict__ Bt,
             short* __restrict__ Cb, float* __restrict__ Cf,
             const float* __restrict__ bias, const float* __restrict__ resid,
             int M, int N, int K, int tilesN, int nsplit)
{
    __shared__ __align__(16) short As[128 * 64];   // 16 KiB
    __shared__ __align__(16) short Bs[128 * 64];   // 16 KiB

    int wg = blockIdx.x;
    {
        const int nwg = gridDim.x;
        const int q = nwg >> 3, r = nwg & 7;
        const int xcd = wg & 7, loc = wg >> 3;
        wg = (xcd < r ? xcd * (q + 1) : r * (q + 1) + (xcd - r) * q) + loc;
    }
    const int ntiles = gridDim.x / nsplit;
    const int sp   = wg / ntiles;
    const int tile = wg - sp * ntiles;
    const int tm = tile / tilesN, tn = tile - tm * tilesN;
    const size_t bm = (size_t)tm * 128, bn = (size_t)tn * 128;
    const int Ks   = K / nsplit;
    const int kbeg = sp * Ks;

    const int tid  = threadIdx.x;
    const int wave = tid >> 6;
    const int lane = tid & 63;
    const int quad = lane >> 4;
    const int l16  = lane & 15;
    const int wm = wave >> 1, wn = wave & 1;

    floatx4 acc[4][4];
#pragma unroll
    for (int i = 0; i < 4; i++)
#pragma unroll
        for (int j = 0; j < 4; j++)
            acc[i][j] = (floatx4){0.f, 0.f, 0.f, 0.f};

    const int srow = tid >> 3;               // 0..31
    const int gsrc = (tid & 7) ^ (srow & 7);
    const short* sA = A  + (bm + srow) * (size_t)K + kbeg + gsrc * 8;
    const short* sB = Bt + (bn + srow) * (size_t)K + kbeg + gsrc * 8;
    const int dstw = wave * 512;

    const int g0 = ((quad    ) ^ (l16 & 7)) * 8;
    const int g1 = ((quad + 4) ^ (l16 & 7)) * 8;

    for (int k0 = 0; k0 < Ks; k0 += 64) {
#pragma unroll
        for (int c = 0; c < 4; ++c)
            load_lds16(sA + (size_t)(c * 32) * K + k0, &As[c * 2048 + dstw]);
#pragma unroll
        for (int c = 0; c < 4; ++c)
            load_lds16(sB + (size_t)(c * 32) * K + k0, &Bs[c * 2048 + dstw]);
        __syncthreads();
        {
            shortx8 af[4], bf[4];
#pragma unroll
            for (int mi = 0; mi < 4; mi++)
                af[mi] = *(const shortx8*)&As[(wm * 64 + mi * 16 + l16) * 64 + g0];
#pragma unroll
            for (int ni = 0; ni < 4; ni++)
                bf[ni] = *(const shortx8*)&Bs[(wn * 64 + ni * 16 + l16) * 64 + g0];
#pragma unroll
            for (int mi = 0; mi < 4; mi++)
#pragma unroll
                for (int ni = 0; ni < 4; ni++)
                    acc[mi][ni] = __builtin_amdgcn_mfma_f32_16x16x32_bf16(
                        af[mi], bf[ni], acc[mi][ni], 0, 0, 0);
        }
        {
            shortx8 af[4], bf[4];
#pragma unroll
            for (int mi = 0; mi < 4; mi++)
                af[mi] = *(const shortx8*)&As[(wm * 64 + mi * 16 + l16) * 64 + g1];
#pragma unroll
            for (int ni = 0; ni < 4; ni++)
                bf[ni] = *(const shortx8*)&Bs[(wn * 64 + ni * 16 + l16) * 64 + g1];
#pragma unroll
            for (int mi = 0; mi < 4; mi++)
#pragma unroll
                for (int ni = 0; ni < 4; ni++)
                    acc[mi][ni] = __builtin_amdgcn_mfma_f32_16x16x32_bf16(
                        af[mi], bf[ni], acc[mi][ni], 0, 0, 0);
        }
        __syncthreads();
    }

#pragma unroll
    for (int mi = 0; mi < 4; mi++) {
#pragma unroll
        for (int ni = 0; ni < 4; ni++) {
            const size_t row0 = bm + wm * 64 + mi * 16 + quad * 4;
            const size_t col  = bn + wn * 64 + ni * 16 + l16;
#pragma unroll
            for (int r2 = 0; r2 < 4; r2++) {
                float v = acc[mi][ni][r2];
                const size_t idx = (row0 + r2) * (size_t)N + col;
                if (EPI == 0) {
                    Cb[idx] = f2bf(v);
                } else if (EPI == 1) {
                    v += bias[col];
                    Cb[idx] = f2bf(v > 0.f ? v : 0.f);
                } else if (EPI == 2) {
                    Cf[idx] = resid[idx] + v;
                } else {  // EPI 4
                    if (sp == 0) v += bias[col];
                    atomicAdd(&Cf[idx], v);
                }
            }
        }
    }
}

// =====================================================================
// 256x128 bf16 GEMM, BK=64: higher arithmetic intensity (0.75x staged
// bytes vs 128x128).  512 threads = 8 waves (4M x 2N, 64x64 each).
// __launch_bounds__(512, 4): VGPR cap 128 >= ~116 needed -> NO SPILLS
// (R14's (512,6) cap of ~85 spilled acc to scratch: 1.4 GB scratch
// writes, MfmaUtil 5.9%).  2 blocks/CU = 16 waves/CU (same wave count
// as gemm_bt) at 1.37x compute per staged byte.
// Used for large-grid GEMMs: QKV (768 WGs), FF1 (1024 WGs).
// EPI 0: store bf16;  EPI 1: +bias, relu, store bf16
// =====================================================================
template <int EPI>
__global__ __launch_bounds__(512, 4)
void gemm_big(const short* __restrict__ A, const short* __restrict__ Bt,
              short* __restrict__ Cb, float* __restrict__ Cf,
              const float* __restrict__ bias, const float* __restrict__ resid,
              int M, int N, int K, int tilesN, int nsplit)
{
    __shared__ __align__(16) short As[256 * 64];   // 32 KiB
    __shared__ __align__(16) short Bs[128 * 64];   // 16 KiB

    int wg = blockIdx.x;
    {
        const int nwg = gridDim.x;
        const int q = nwg >> 3, r = nwg & 7;
        const int xcd = wg & 7, loc = wg >> 3;
        wg = (xcd < r ? xcd * (q + 1) : r * (q + 1) + (xcd - r) * q) + loc;
    }
    const int ntiles = gridDim.x / nsplit;
    const int sp   = wg / ntiles;
    const int tile = wg - sp * ntiles;
    const int tm = tile / tilesN, tn = tile - tm * tilesN;
    const size_t bm = (size_t)tm * 256, bn = (size_t)tn * 128;
    const int Ks   = K / nsplit;
    const int kbeg = sp * Ks;

    const int tid  = threadIdx.x;
    const int wave = tid >> 6;          // 0..7
    const int lane = tid & 63;
    const int quad = lane >> 4;
    const int l16  = lane & 15;
    const int wm = wave >> 1, wn = wave & 1;   // 4M x 2N, 64x64 per wave

    floatx4 acc[4][4];
#pragma unroll
    for (int i = 0; i < 4; i++)
#pragma unroll
        for (int j = 0; j < 4; j++)
            acc[i][j] = (floatx4){0.f, 0.f, 0.f, 0.f};

    // staging: 512 threads -> row = c*64 + (tid>>3) (0..63), slot = tid&7.
    // source granule pre-swizzled: (tid&7) ^ ((tid>>3)&7) == slot ^ (row&7).
    const int srow = tid >> 3;               // 0..63
    const int gsrc = (tid & 7) ^ (srow & 7);
    const short* sA = A  + (bm + srow) * (size_t)K + kbeg + gsrc * 8;
    const short* sB = Bt + (bn + srow) * (size_t)K + kbeg + gsrc * 8;
    const int dstw = wave * 512;             // 8 waves x 512 shorts = 4096/call

    const int g0 = ((quad    ) ^ (l16 & 7)) * 8;
    const int g1 = ((quad + 4) ^ (l16 & 7)) * 8;

    for (int k0 = 0; k0 < Ks; k0 += 64) {
        // A: 4 calls x 64 rows; B: 2 calls x 64 rows (each call 4096 shorts)
#pragma unroll
        for (int c = 0; c < 4; ++c)
            load_lds16(sA + (size_t)(c * 64) * K + k0, &As[c * 4096 + dstw]);
#pragma unroll
        for (int c = 0; c < 2; ++c)
            load_lds16(sB + (size_t)(c * 64) * K + k0, &Bs[c * 4096 + dstw]);
        __syncthreads();
        {
            shortx8 af[4], bf[4];
#pragma unroll
            for (int mi = 0; mi < 4; mi++)
                af[mi] = *(const shortx8*)&As[(wm * 64 + mi * 16 + l16) * 64 + g0];
#pragma unroll
            for (int ni = 0; ni < 4; ni++)
                bf[ni] = *(const shortx8*)&Bs[(wn * 64 + ni * 16 + l16) * 64 + g0];
#pragma unroll
            for (int mi = 0; mi < 4; mi++)
#pragma unroll
                for (int ni = 0; ni < 4; ni++)
                    acc[mi][ni] = __builtin_amdgcn_mfma_f32_16x16x32_bf16(
                        af[mi], bf[ni], acc[mi][ni], 0, 0, 0);
        }
        {
            shortx8 af[4], bf[4];
#pragma unroll
            for (int mi = 0; mi < 4; mi++)
                af[mi] = *(const shortx8*)&As[(wm * 64 + mi * 16 + l16) * 64 + g1];
#pragma unroll
            for (int ni = 0; ni < 4; ni++)
                bf[ni] = *(const shortx8*)&Bs[(wn * 64 + ni * 16 + l16) * 64 + g1];
#pragma unroll
            for (int mi = 0; mi < 4; mi++)
#pragma unroll
                for (int ni = 0; ni < 4; ni++)
                    acc[mi][ni] = __builtin_amdgcn_mfma_f32_16x16x32_bf16(
                        af[mi], bf[ni], acc[mi][ni], 0, 0, 0);
        }
        __syncthreads();
    }

#pragma unroll
    for (int mi = 0; mi < 4; mi++) {
#pragma unroll
        for (int ni = 0; ni < 4; ni++) {
            const size_t row0 = bm + wm * 64 + mi * 16 + quad * 4;
            const size_t col  = bn + wn * 64 + ni * 16 + l16;
#pragma unroll
            for (int r2 = 0; r2 < 4; r2++) {
                float v = acc[mi][ni][r2];
                const size_t idx = (row0 + r2) * (size_t)N + col;
                if (EPI == 0) {
                    Cb[idx] = f2bf(v);
                } else {  // EPI 1
                    v += bias[col];
                    Cb[idx] = f2bf(v > 0.f ? v : 0.f);
                }
            }
        }
    }
}

// =====================================================================
// V transpose: qkv v-part -> vt[b][h][64 d][2048 s] bf16
// =====================================================================
__global__ __launch_bounds__(256)
void transpose_v(const short* __restrict__ qkv, short* __restrict__ vt)
{
    __shared__ __align__(16) short tile[64][65];
    const int st = blockIdx.x, h = blockIdx.y, b = blockIdx.z;
    const int t = threadIdx.x;
    for (int i = 0; i < 2; i++) {
        const int idx = i * 256 + t;
        const int s = idx >> 3, dg = idx & 7;
        shortx8 val = *(const shortx8*)&qkv[(size_t)(b * 2048 + st * 64 + s) * 3072
                                           + 2048 + h * 64 + dg * 8];
        for (int u = 0; u < 8; u++) tile[s][dg * 8 + u] = val[u];
    }
    __syncthreads();
    const int d = t >> 2, sg = (t & 3) * 16;
    shortx8 lo, hi;
    for (int i = 0; i < 8; i++) {
        lo[i] = tile[sg + i][d];
        hi[i] = tile[sg + 8 + i][d];
    }
    const size_t base = ((size_t)(b * 16 + h) * 64 + d) * 2048 + st * 64 + sg;
    *(shortx8*)&vt[base]     = lo;
    *(shortx8*)&vt[base + 8] = hi;
}

// =====================================================================
// Flash attention v6 (unchanged): 32x32x16 MFMA, 8 waves x 32 q-rows.
// =====================================================================
__global__ __launch_bounds__(512, 4)
void attention_kernel(const short* __restrict__ qkv, const short* __restrict__ vt,
                      short* __restrict__ ctx)
{
    const int qt = blockIdx.x, h = blockIdx.y, b = blockIdx.z;
    const int tid  = threadIdx.x;
    const int wave = tid >> 6;          // 0..7
    const int lane = tid & 63;
    const int l32  = lane & 31;
    const int hf   = lane >> 5;         // 0/1

    __shared__ __align__(16) short Ks[64 * 72];        // [kseq][d], stride 72
    __shared__ __align__(16) short Vs[64 * 72];        // [d][s],   stride 72
    __shared__ __align__(16) short Ps[8][32 * 72];     // per-wave P [q][s], stride 72

    const int q0 = qt * 256 + wave * 32;
    const float qscale = 0.125f * 1.44269504088896f;
    const short* qrow = qkv + (size_t)(b * 2048 + q0 + l32) * 3072 + h * 64;
    shortx8 qf[4];
    for (int dk = 0; dk < 4; dk++) {
        shortx8 raw = *(const shortx8*)&qrow[dk * 16 + hf * 8];
        for (int j = 0; j < 8; j++) raw[j] = f2bf(bf2f(raw[j]) * qscale);
        qf[dk] = raw;
    }

    floatx16 accO[2];
    for (int t = 0; t < 2; t++)
        for (int r = 0; r < 16; r++) accO[t][r] = 0.f;
    float lsum = 0.f;

    const short* kbase = qkv + (size_t)(b * 2048) * 3072 + 1024 + h * 64;
    const short* vbase = vt + ((size_t)(b * 16 + h) * 64) * 2048;
    short* const psw = &Ps[wave][0];
    unsigned* const pswd = (unsigned*)psw;

    const int ss = tid >> 3, sdg = tid & 7;

    for (int kt = 0; kt < 32; ++kt) {
        __syncthreads();
        {
            shortx8 kv = *(const shortx8*)&kbase[(size_t)(kt * 64 + ss) * 3072 + sdg * 8];
            *(shortx8*)&Ks[ss * 72 + sdg * 8] = kv;
            shortx8 vv = *(const shortx8*)&vbase[(size_t)ss * 2048 + kt * 64 + sdg * 8];
            *(shortx8*)&Vs[ss * 72 + sdg * 8] = vv;
        }
        __syncthreads();

        for (int t = 0; t < 2; t++) {
            floatx16 c;
            for (int r = 0; r < 16; r++) c[r] = 0.f;
            for (int dk = 0; dk < 4; dk++) {
                shortx8 kf = *(const shortx8*)&Ks[(t * 32 + l32) * 72 + dk * 16 + hf * 8];
                c = __builtin_amdgcn_mfma_f32_32x32x16_bf16(kf, qf[dk], c, 0, 0, 0);
            }
            for (int R = 0; R < 4; R++) {
                float2 a, bb;
                a.x  = fast_exp2(c[4 * R + 0]);
                a.y  = fast_exp2(c[4 * R + 1]);
                bb.x = fast_exp2(c[4 * R + 2]);
                bb.y = fast_exp2(c[4 * R + 3]);
                lsum += (a.x + a.y) + (bb.x + bb.y);
                union { __hip_bfloat162 h2[2]; uint2 u; } pk;
                pk.h2[0] = __float22bfloat162_rn(a);
                pk.h2[1] = __float22bfloat162_rn(bb);
                *(uint2*)&pswd[l32 * 36 + t * 16 + 4 * R + 2 * hf] = pk.u;
            }
        }
        asm volatile("s_waitcnt lgkmcnt(0)" ::: "memory");

        shortx8 pf[4];
        for (int sk = 0; sk < 4; sk++)
            pf[sk] = *(const shortx8*)&psw[l32 * 72 + sk * 16 + hf * 8];

        for (int t = 0; t < 2; t++) {
            floatx16 c = accO[t];
            for (int sk = 0; sk < 4; sk++) {
                shortx8 vf = *(const shortx8*)&Vs[(t * 32 + l32) * 72 + sk * 16 + hf * 8];
                c = __builtin_amdgcn_mfma_f32_32x32x16_bf16(vf, pf[sk], c, 0, 0, 0);
            }
            accO[t] = c;
        }
    }

    const float lfull = lsum + __shfl_xor(lsum, 32);
    const float inv = 1.0f / lfull;
    const size_t crow = (size_t)(b * 2048 + q0 + l32) * 1024 + h * 64;
    for (int t = 0; t < 2; t++)
        for (int R = 0; R < 4; R++) {
            float2 a, bb;
            a.x  = accO[t][4 * R + 0] * inv;
            a.y  = accO[t][4 * R + 1] * inv;
            bb.x = accO[t][4 * R + 2] * inv;
            bb.y = accO[t][4 * R + 3] * inv;
            union { __hip_bfloat162 h2[2]; uint2 u; } pk;
            pk.h2[0] = __float22bfloat162_rn(a);
            pk.h2[1] = __float22bfloat162_rn(bb);
            *(uint2*)&ctx[crow + t * 32 + 8 * R + 4 * hf] = pk.u;
        }
}

// =====================================================================
// launch
// =====================================================================
extern "C" void kernel_launch(void* const* d_in, const int* in_sizes, int n_in,
                              void* d_out, int out_size, void* d_ws, size_t ws_size,
                              hipStream_t stream)
{
    const float* x   = (const float*)d_in[0];
    const float* Wq  = (const float*)d_in[1];
    const float* Wk  = (const float*)d_in[2];
    const float* Wv  = (const float*)d_in[3];
    const float* Wo  = (const float*)d_in[4];
    const float* W1  = (const float*)d_in[5];
    const float* b1  = (const float*)d_in[6];
    const float* W2  = (const float*)d_in[7];
    const float* b2  = (const float*)d_in[8];
    const float* g1  = (const float*)d_in[9];
    const float* be1 = (const float*)d_in[10];
    const float* g2  = (const float*)d_in[11];
    const float* be2 = (const float*)d_in[12];
    float* out = (float*)d_out;
    char*  ws  = (char*)d_ws;

    const size_t MiB = 1u << 20;
    short* regA   = (short*)(ws);                 // 16 MiB: ln1 -> ctx -> ln2
    short* qkv    = (short*)(ws + 16 * MiB);      // 48 MiB
    short* vt     = (short*)(ws + 64 * MiB);      // 16 MiB
    short* ff1    = qkv;                          // 64 MiB alias (qkv+vt dead)
    short* Wqkv_t = (short*)(ws + 80 * MiB);      // 6 MiB
    short* Wo_t   = (short*)(ws + 86 * MiB);      // 2 MiB
    short* W1_t   = (short*)(ws + 88 * MiB);      // 8 MiB
    short* W2_t   = (short*)(ws + 96 * MiB);      // 8 MiB  (total 104 MiB)

    const dim3 blk(256);

    // weights -> bf16 BT layout
    transpose_w<<<dim3(32, 32),  blk, 0, stream>>>(Wq, Wqkv_t,                  1024, 1024);
    transpose_w<<<dim3(32, 32),  blk, 0, stream>>>(Wk, Wqkv_t + 1024 * 1024,    1024, 1024);
    transpose_w<<<dim3(32, 32),  blk, 0, stream>>>(Wv, Wqkv_t + 2 * 1024 * 1024,1024, 1024);
    transpose_w<<<dim3(32, 32),  blk, 0, stream>>>(Wo, Wo_t,                    1024, 1024);
    transpose_w<<<dim3(128, 32), blk, 0, stream>>>(W1, W1_t,                    1024, 4096);
    transpose_w<<<dim3(32, 128), blk, 0, stream>>>(W2, W2_t,                    4096, 1024);

    // LN1
    ln_bf16<<<8192, blk, 0, stream>>>(x, g1, be1, regA);
    // QKV: [8192,1024]@[3072,1024]^T -> 256x128 tiles: 32x24 = 768 WGs
    gemm_big<0><<<dim3(768), dim3(512), 0, stream>>>(regA, Wqkv_t, qkv, nullptr,
                                                     nullptr, nullptr, 8192, 3072, 1024, 24, 1);
    // V^T
    transpose_v<<<dim3(32, 16, 4), blk, 0, stream>>>(qkv, vt);
    // attention -> ctx (regA)
    attention_kernel<<<dim3(8, 16, 4), dim3(512), 0, stream>>>(qkv, vt, regA);
    // attn_out @ Wo + x -> out (fp32), fused store: 64x8 = 512 WGs (128^2)
    gemm_bt<2><<<dim3(512), blk, 0, stream>>>(regA, Wo_t, nullptr, out,
                                              nullptr, x, 8192, 1024, 1024, 8, 1);
    // LN2 -> regA
    ln_bf16<<<8192, blk, 0, stream>>>(out, g2, be2, regA);
    // FF1: relu(ln2 @ W1 + b1) -> ff1 (bf16): 256x128 tiles: 32x32 = 1024 WGs
    gemm_big<1><<<dim3(1024), dim3(512), 0, stream>>>(regA, W1_t, ff1, nullptr,
                                                      b1, nullptr, 8192, 4096, 1024, 32, 1);
    // FF2 split-K=2: out += ff1 @ W2 (+b2 on split 0): 64x8x2 = 1024 WGs (128^2)
    gemm_bt<4><<<dim3(1024), blk, 0, stream>>>(ff1, W2_t, nullptr, out,
                                               b2, nullptr, 8192, 1024, 4096, 8, 2);
}